// Round 1
// baseline (133.727 us; speedup 1.0000x reference)
//
#include <hip/hip_runtime.h>
#include <math.h>

#define TPB 256
#define MAX_NB 4096   // max staged opposing-set points (64 KiB LDS as float4)

// Pack recon -> preds (float4 w=|p|^2); transform src -> gts (float4 w=|p|^2).
__global__ __launch_bounds__(TPB) void prep_kernel(
    const float* __restrict__ recon,   // B*M*3
    const float* __restrict__ src,     // B*N*3
    const float* __restrict__ T,       // B*16
    float4* __restrict__ preds,        // B*M
    float4* __restrict__ gts,          // B*N
    int B, int N, int M)
{
    int idx = blockIdx.x * TPB + threadIdx.x;
    int totG = B * N;
    int totP = B * M;
    if (idx < totG) {
        int b = idx / N;
        const float* Tb = T + b * 16;
        float x = src[3*idx + 0], y = src[3*idx + 1], z = src[3*idx + 2];
        // gts[b,n,k] = sum_d src[b,n,d] * R[b,k,d] + t[b,k];  R row k = T[4k..4k+2], t[k] = T[4k+3]
        float gx = fmaf(Tb[0], x, fmaf(Tb[1], y, fmaf(Tb[2],  z, Tb[3])));
        float gy = fmaf(Tb[4], x, fmaf(Tb[5], y, fmaf(Tb[6],  z, Tb[7])));
        float gz = fmaf(Tb[8], x, fmaf(Tb[9], y, fmaf(Tb[10], z, Tb[11])));
        gts[idx] = make_float4(gx, gy, gz, fmaf(gx, gx, fmaf(gy, gy, gz * gz)));
    } else if (idx - totG < totP) {
        int k = idx - totG;
        float x = recon[3*k + 0], y = recon[3*k + 1], z = recon[3*k + 2];
        preds[k] = make_float4(x, y, z, fmaf(x, x, fmaf(y, y, z * z)));
    }
}

// dir 0: A = gts,  Bset = preds  -> sum_n min_m  (loss_2)
// dir 1: A = preds, Bset = gts   -> sum_m min_n  (loss_1)
__global__ __launch_bounds__(TPB) void chamfer_kernel(
    const float4* __restrict__ gts,
    const float4* __restrict__ preds,
    float* __restrict__ out,
    int B, int N, int M)
{
    __shared__ float4 sB[MAX_NB];

    const int dir = blockIdx.z;
    const int b   = blockIdx.y;
    const int NA  = (dir == 0) ? N : M;
    const int NB  = (dir == 0) ? M : N;
    const float4* __restrict__ Aset = (dir == 0) ? (gts   + (size_t)b * N) : (preds + (size_t)b * M);
    const float4* __restrict__ Bset = (dir == 0) ? (preds + (size_t)b * M) : (gts   + (size_t)b * N);

    // Stage opposing set into LDS (coalesced 16B loads).
    for (int t = threadIdx.x; t < NB; t += TPB) sB[t] = Bset[t];
    __syncthreads();

    const int i = blockIdx.x * TPB + threadIdx.x;
    float msum = 0.0f;
    if (i < NA) {
        const float4 a = Aset[i];
        // 4 independent accumulators break the fmin dependency chain.
        float m0 = INFINITY, m1 = INFINITY, m2 = INFINITY, m3 = INFINITY;
        int j = 0;
        const int nb8 = NB & ~7;
        for (; j < nb8; j += 8) {
            // All lanes read the same address -> LDS broadcast (conflict-free).
            float4 b0 = sB[j+0], b1 = sB[j+1], b2 = sB[j+2], b3 = sB[j+3];
            float4 b4 = sB[j+4], b5 = sB[j+5], b6 = sB[j+6], b7 = sB[j+7];
            // d = (|a|^2 + |b|^2) - 2 * a.b  — matches reference xx+yy-2zz.
            float d0 = fmaf(-2.0f, fmaf(a.z, b0.z, fmaf(a.y, b0.y, a.x * b0.x)), a.w + b0.w);
            float d1 = fmaf(-2.0f, fmaf(a.z, b1.z, fmaf(a.y, b1.y, a.x * b1.x)), a.w + b1.w);
            float d2 = fmaf(-2.0f, fmaf(a.z, b2.z, fmaf(a.y, b2.y, a.x * b2.x)), a.w + b2.w);
            float d3 = fmaf(-2.0f, fmaf(a.z, b3.z, fmaf(a.y, b3.y, a.x * b3.x)), a.w + b3.w);
            float d4 = fmaf(-2.0f, fmaf(a.z, b4.z, fmaf(a.y, b4.y, a.x * b4.x)), a.w + b4.w);
            float d5 = fmaf(-2.0f, fmaf(a.z, b5.z, fmaf(a.y, b5.y, a.x * b5.x)), a.w + b5.w);
            float d6 = fmaf(-2.0f, fmaf(a.z, b6.z, fmaf(a.y, b6.y, a.x * b6.x)), a.w + b6.w);
            float d7 = fmaf(-2.0f, fmaf(a.z, b7.z, fmaf(a.y, b7.y, a.x * b7.x)), a.w + b7.w);
            m0 = fminf(m0, d0); m1 = fminf(m1, d1); m2 = fminf(m2, d2); m3 = fminf(m3, d3);
            m0 = fminf(m0, d4); m1 = fminf(m1, d5); m2 = fminf(m2, d6); m3 = fminf(m3, d7);
        }
        for (; j < NB; ++j) {
            float4 bj = sB[j];
            float d = fmaf(-2.0f, fmaf(a.z, bj.z, fmaf(a.y, bj.y, a.x * bj.x)), a.w + bj.w);
            m0 = fminf(m0, d);
        }
        msum = fminf(fminf(m0, m1), fminf(m2, m3));
    }

    // Block-sum of per-thread mins -> one atomicAdd per block.
    float s = msum;
    #pragma unroll
    for (int off = 32; off > 0; off >>= 1) s += __shfl_down(s, off);

    __syncthreads();                 // all sB reads done before aliasing as scratch
    float* red = (float*)sB;
    if ((threadIdx.x & 63) == 0) red[threadIdx.x >> 6] = s;
    __syncthreads();
    if (threadIdx.x == 0) {
        atomicAdd(out, red[0] + red[1] + red[2] + red[3]);
    }
}

extern "C" void kernel_launch(void* const* d_in, const int* in_sizes, int n_in,
                              void* d_out, int out_size, void* d_ws, size_t ws_size,
                              hipStream_t stream)
{
    const float* recon = (const float*)d_in[0];   // (B, M, 3)
    const float* src   = (const float*)d_in[1];   // (B, N, 3)
    const float* T     = (const float*)d_in[2];   // (B, 4, 4)

    const int B = in_sizes[2] / 16;
    const int M = in_sizes[0] / (B * 3);
    const int N = in_sizes[1] / (B * 3);

    float4* preds = (float4*)d_ws;                    // B*M float4
    float4* gts   = preds + (size_t)B * M;            // B*N float4
    float*  out   = (float*)d_out;

    hipMemsetAsync(out, 0, sizeof(float) * out_size, stream);

    const int tot = B * (N + M);
    prep_kernel<<<dim3((tot + TPB - 1) / TPB), dim3(TPB), 0, stream>>>(
        recon, src, T, preds, gts, B, N, M);

    const int NAmax = (N > M) ? N : M;
    dim3 grid((NAmax + TPB - 1) / TPB, B, 2);
    chamfer_kernel<<<grid, dim3(TPB), 0, stream>>>(gts, preds, out, B, N, M);
}

// Round 3
// 92.765 us; speedup vs baseline: 1.4416x; 1.4416x over previous
//
#include <hip/hip_runtime.h>
#include <math.h>

#define TPB      256
#define KA       4                 // queries per thread (register blocking)
#define QPB      (TPB * KA)        // 1024 queries per block
#define C_CHUNKS 16                // B-set split across blocks
#define MAX_CPTS 512               // LDS cap: 512 float4 = 8 KiB

// Pack recon -> preds (float4, w=|p|^2); transform src -> gts (float4, w=|p|^2).
// Also zeroes d_out (replaces a separate memset dispatch).
__global__ __launch_bounds__(TPB) void prep_kernel(
    const float* __restrict__ recon,   // B*M*3
    const float* __restrict__ src,     // B*N*3
    const float* __restrict__ T,       // B*16
    float4* __restrict__ preds,        // B*M
    float4* __restrict__ gts,          // B*N
    float* __restrict__ out, int out_n,
    int B, int N, int M)
{
    int idx = blockIdx.x * TPB + threadIdx.x;
    if (idx < out_n) out[idx] = 0.0f;
    int totG = B * N;
    int totP = B * M;
    if (idx < totG) {
        int b = idx / N;
        const float* Tb = T + b * 16;
        float x = src[3*idx + 0], y = src[3*idx + 1], z = src[3*idx + 2];
        float gx = fmaf(Tb[0], x, fmaf(Tb[1], y, fmaf(Tb[2],  z, Tb[3])));
        float gy = fmaf(Tb[4], x, fmaf(Tb[5], y, fmaf(Tb[6],  z, Tb[7])));
        float gz = fmaf(Tb[8], x, fmaf(Tb[9], y, fmaf(Tb[10], z, Tb[11])));
        gts[idx] = make_float4(gx, gy, gz, fmaf(gx, gx, fmaf(gy, gy, gz * gz)));
    } else if (idx - totG < totP) {
        int k = idx - totG;
        float x = recon[3*k + 0], y = recon[3*k + 1], z = recon[3*k + 2];
        preds[k] = make_float4(x, y, z, fmaf(x, x, fmaf(y, y, z * z)));
    }
}

// Each block: one query-tile (QPB queries) x one B-chunk (NB/C_CHUNKS points).
// Writes per-chunk partial mins to partial[c][gq]; no atomics.
// dir 0: A = gts (N queries), B = preds.  dir 1: A = preds (M queries), B = gts.
// Launch: blockIdx.x = qt * C_CHUNKS + c.
__global__ __launch_bounds__(TPB) void chamfer_kernel(
    const float4* __restrict__ gts,
    const float4* __restrict__ preds,
    float* __restrict__ partial,       // [C_CHUNKS][GQ]
    int B, int N, int M, int GQ)
{
    __shared__ float4 sB[MAX_CPTS];

    const int dir = blockIdx.z;
    const int b   = blockIdx.y;
    const int c   = blockIdx.x % C_CHUNKS;
    const int qt  = blockIdx.x / C_CHUNKS;

    const int NA  = (dir == 0) ? N : M;
    const int NB_ = (dir == 0) ? M : N;
    if (qt * QPB >= NA) return;   // uniform across block

    const float4* __restrict__ Aset = (dir == 0) ? (gts   + (size_t)b * N) : (preds + (size_t)b * M);
    const float4* __restrict__ Bset = (dir == 0) ? (preds + (size_t)b * M) : (gts   + (size_t)b * N);
    const int gq_base = ((dir == 0) ? 0 : B * N) + b * NA;

    // Stage this block's B-chunk into LDS.
    const int cpts = (NB_ + C_CHUNKS - 1) / C_CHUNKS;
    const int j0   = c * cpts;
    const int jn   = (j0 + cpts <= NB_) ? cpts : (NB_ - j0);
    for (int t = threadIdx.x; t < jn; t += TPB) sB[t] = Bset[j0 + t];
    __syncthreads();

    // Load KA queries (coalesced, stride TPB); hoist -2*xyz.
    int   qi[KA];
    float a2x[KA], a2y[KA], a2z[KA], aw[KA];
    #pragma unroll
    for (int k = 0; k < KA; ++k) {
        qi[k] = qt * QPB + k * TPB + (int)threadIdx.x;
        float4 a = (qi[k] < NA) ? Aset[qi[k]] : make_float4(0.f, 0.f, 0.f, 0.f);
        a2x[k] = -2.0f * a.x; a2y[k] = -2.0f * a.y; a2z[k] = -2.0f * a.z; aw[k] = a.w;
    }

    float mA[KA], mB[KA];
    #pragma unroll
    for (int k = 0; k < KA; ++k) { mA[k] = INFINITY; mB[k] = INFINITY; }

    int j = 0;
    const int jn4 = jn & ~3;
    for (; j < jn4; j += 4) {
        // Same address across all lanes -> LDS broadcast, conflict-free.
        float4 b0 = sB[j+0], b1 = sB[j+1], b2 = sB[j+2], b3 = sB[j+3];
        #pragma unroll
        for (int k = 0; k < KA; ++k) {
            // d = (aw + bw) - 2*(ax bx + ay by + az bz): 4 fma + 1 add + fmin
            float d0 = fmaf(a2x[k], b0.x, fmaf(a2y[k], b0.y, fmaf(a2z[k], b0.z, aw[k] + b0.w)));
            float d1 = fmaf(a2x[k], b1.x, fmaf(a2y[k], b1.y, fmaf(a2z[k], b1.z, aw[k] + b1.w)));
            float d2 = fmaf(a2x[k], b2.x, fmaf(a2y[k], b2.y, fmaf(a2z[k], b2.z, aw[k] + b2.w)));
            float d3 = fmaf(a2x[k], b3.x, fmaf(a2y[k], b3.y, fmaf(a2z[k], b3.z, aw[k] + b3.w)));
            mA[k] = fminf(mA[k], d0); mB[k] = fminf(mB[k], d1);
            mA[k] = fminf(mA[k], d2); mB[k] = fminf(mB[k], d3);
        }
    }
    for (; j < jn; ++j) {
        float4 bj = sB[j];
        #pragma unroll
        for (int k = 0; k < KA; ++k) {
            float d = fmaf(a2x[k], bj.x, fmaf(a2y[k], bj.y, fmaf(a2z[k], bj.z, aw[k] + bj.w)));
            mA[k] = fminf(mA[k], d);
        }
    }

    // Coalesced partial-min writes: one per query per chunk.
    #pragma unroll
    for (int k = 0; k < KA; ++k) {
        if (qi[k] < NA)
            partial[(size_t)c * GQ + gq_base + qi[k]] = fminf(mA[k], mB[k]);
    }
}

// Combine: per-query min over chunks, then global sum.
__global__ __launch_bounds__(TPB) void reduce_kernel(
    const float* __restrict__ partial, float* __restrict__ out, int GQ)
{
    int q = blockIdx.x * TPB + threadIdx.x;
    float m = 0.0f;
    if (q < GQ) {
        m = partial[q];
        #pragma unroll
        for (int c = 1; c < C_CHUNKS; ++c)
            m = fminf(m, partial[(size_t)c * GQ + q]);
    }
    // wave reduce (64 lanes)
    #pragma unroll
    for (int off = 32; off > 0; off >>= 1) m += __shfl_down(m, off);
    __shared__ float red[TPB / 64];
    if ((threadIdx.x & 63) == 0) red[threadIdx.x >> 6] = m;
    __syncthreads();
    if (threadIdx.x == 0) {
        float s = 0.0f;
        #pragma unroll
        for (int w = 0; w < TPB / 64; ++w) s += red[w];
        atomicAdd(out, s);
    }
}

extern "C" void kernel_launch(void* const* d_in, const int* in_sizes, int n_in,
                              void* d_out, int out_size, void* d_ws, size_t ws_size,
                              hipStream_t stream)
{
    const float* recon = (const float*)d_in[0];   // (B, M, 3)
    const float* src   = (const float*)d_in[1];   // (B, N, 3)
    const float* T     = (const float*)d_in[2];   // (B, 4, 4)

    const int B = in_sizes[2] / 16;
    const int M = in_sizes[0] / (B * 3);
    const int N = in_sizes[1] / (B * 3);
    const int GQ = B * (N + M);

    float4* preds   = (float4*)d_ws;                          // B*M
    float4* gts     = preds + (size_t)B * M;                  // B*N
    float*  partial = (float*)(gts + (size_t)B * N);          // C_CHUNKS * GQ
    float*  out     = (float*)d_out;

    const int tot = GQ;  // one thread per packed point
    prep_kernel<<<dim3((tot + TPB - 1) / TPB), dim3(TPB), 0, stream>>>(
        recon, src, T, preds, gts, out, out_size, B, N, M);

    const int NAmax = (N > M) ? N : M;
    const int QT    = (NAmax + QPB - 1) / QPB;
    dim3 grid(QT * C_CHUNKS, B, 2);
    chamfer_kernel<<<grid, dim3(TPB), 0, stream>>>(gts, preds, partial, B, N, M, GQ);

    reduce_kernel<<<dim3((GQ + TPB - 1) / TPB), dim3(TPB), 0, stream>>>(partial, out, GQ);
}

// Round 6
// 89.685 us; speedup vs baseline: 1.4911x; 1.0343x over previous
//
#include <hip/hip_runtime.h>
#include <math.h>

#define TPB      256
#define KA       8                 // queries per thread (register blocking)
#define QPB      (TPB * KA)        // 2048 queries per block
#define C_CHUNKS 32                // B-set split across blocks
#define MAX_CPTS 128               // LDS cap: 128 float4 = 2 KiB

// Pack recon -> preds (float4, w=|p|^2); transform src -> gts (float4, w=|p|^2).
// Also zeroes d_out (replaces a separate memset dispatch).
__global__ __launch_bounds__(TPB) void prep_kernel(
    const float* __restrict__ recon,   // B*M*3
    const float* __restrict__ src,     // B*N*3
    const float* __restrict__ T,       // B*16
    float4* __restrict__ preds,        // B*M
    float4* __restrict__ gts,          // B*N
    float* __restrict__ out, int out_n,
    int B, int N, int M)
{
    int idx = blockIdx.x * TPB + threadIdx.x;
    if (idx < out_n) out[idx] = 0.0f;
    int totG = B * N;
    int totP = B * M;
    if (idx < totG) {
        int b = idx / N;
        const float* Tb = T + b * 16;
        float x = src[3*idx + 0], y = src[3*idx + 1], z = src[3*idx + 2];
        float gx = fmaf(Tb[0], x, fmaf(Tb[1], y, fmaf(Tb[2],  z, Tb[3])));
        float gy = fmaf(Tb[4], x, fmaf(Tb[5], y, fmaf(Tb[6],  z, Tb[7])));
        float gz = fmaf(Tb[8], x, fmaf(Tb[9], y, fmaf(Tb[10], z, Tb[11])));
        gts[idx] = make_float4(gx, gy, gz, fmaf(gx, gx, fmaf(gy, gy, gz * gz)));
    } else if (idx - totG < totP) {
        int k = idx - totG;
        float x = recon[3*k + 0], y = recon[3*k + 1], z = recon[3*k + 2];
        preds[k] = make_float4(x, y, z, fmaf(x, x, fmaf(y, y, z * z)));
    }
}

// Each block: one query-tile (QPB queries) x one B-chunk (NB/C_CHUNKS points).
// Inner distance uses the aw-hoist: min_j(aw+bw-2ab) = aw + min_j(bw-2ab),
// so per distance = 3 fma + shared min (v_min3 pairs).
// dir 0: A = gts (N queries), B = preds.  dir 1: A = preds (M queries), B = gts.
// Launch: blockIdx.x = qt * C_CHUNKS + c.
__global__ __launch_bounds__(TPB) void chamfer_kernel(
    const float4* __restrict__ gts,
    const float4* __restrict__ preds,
    float* __restrict__ partial,       // [C_CHUNKS][GQ]
    int B, int N, int M, int GQ)
{
    __shared__ float4 sB[MAX_CPTS];

    const int dir = blockIdx.z;
    const int b   = blockIdx.y;
    const int c   = blockIdx.x % C_CHUNKS;
    const int qt  = blockIdx.x / C_CHUNKS;

    const int NA  = (dir == 0) ? N : M;
    const int NB_ = (dir == 0) ? M : N;
    if (qt * QPB >= NA) return;   // uniform across block

    const float4* __restrict__ Aset = (dir == 0) ? (gts   + (size_t)b * N) : (preds + (size_t)b * M);
    const float4* __restrict__ Bset = (dir == 0) ? (preds + (size_t)b * M) : (gts   + (size_t)b * N);
    const int gq_base = ((dir == 0) ? 0 : B * N) + b * NA;

    // Stage this block's B-chunk into LDS (2 KiB).
    const int cpts = (NB_ + C_CHUNKS - 1) / C_CHUNKS;
    const int j0   = c * cpts;
    const int jn   = (j0 + cpts <= NB_) ? cpts : (NB_ - j0);
    for (int t = threadIdx.x; t < jn; t += TPB) sB[t] = Bset[j0 + t];
    __syncthreads();

    // Load KA queries (coalesced, stride TPB); hoist -2*xyz.
    int   qi[KA];
    float a2x[KA], a2y[KA], a2z[KA], aw[KA];
    #pragma unroll
    for (int k = 0; k < KA; ++k) {
        qi[k] = qt * QPB + k * TPB + (int)threadIdx.x;
        float4 a = (qi[k] < NA) ? Aset[qi[k]] : make_float4(0.f, 0.f, 0.f, 0.f);
        a2x[k] = -2.0f * a.x; a2y[k] = -2.0f * a.y; a2z[k] = -2.0f * a.z; aw[k] = a.w;
    }

    // Two accumulators per query: independent min chains (ILP), merged at end.
    float mA[KA], mB[KA];
    #pragma unroll
    for (int k = 0; k < KA; ++k) { mA[k] = INFINITY; mB[k] = INFINITY; }

    int j = 0;
    const int jn4 = jn & ~3;
    for (; j < jn4; j += 4) {
        // Same address across all lanes -> LDS broadcast, conflict-free.
        float4 b0 = sB[j+0], b1 = sB[j+1], b2 = sB[j+2], b3 = sB[j+3];
        #pragma unroll
        for (int k = 0; k < KA; ++k) {
            // e = bw - 2*(ax bx + ay by + az bz): exactly 3 fma (bw rides innermost)
            float d0 = fmaf(a2x[k], b0.x, fmaf(a2y[k], b0.y, fmaf(a2z[k], b0.z, b0.w)));
            float d1 = fmaf(a2x[k], b1.x, fmaf(a2y[k], b1.y, fmaf(a2z[k], b1.z, b1.w)));
            float d2 = fmaf(a2x[k], b2.x, fmaf(a2y[k], b2.y, fmaf(a2z[k], b2.z, b2.w)));
            float d3 = fmaf(a2x[k], b3.x, fmaf(a2y[k], b3.y, fmaf(a2z[k], b3.z, b3.w)));
            // nested fminf pairs -> v_min3_f32 fusion
            mA[k] = fminf(fminf(mA[k], d0), d1);
            mB[k] = fminf(fminf(mB[k], d2), d3);
        }
    }
    for (; j < jn; ++j) {
        float4 bj = sB[j];
        #pragma unroll
        for (int k = 0; k < KA; ++k) {
            float d = fmaf(a2x[k], bj.x, fmaf(a2y[k], bj.y, fmaf(a2z[k], bj.z, bj.w)));
            mA[k] = fminf(mA[k], d);
        }
    }

    // Coalesced partial-min writes (aw added back after the min).
    #pragma unroll
    for (int k = 0; k < KA; ++k) {
        if (qi[k] < NA)
            partial[(size_t)c * GQ + gq_base + qi[k]] = aw[k] + fminf(mA[k], mB[k]);
    }
}

// Combine: per-query min over chunks, then global sum.
__global__ __launch_bounds__(TPB) void reduce_kernel(
    const float* __restrict__ partial, float* __restrict__ out, int GQ)
{
    int q = blockIdx.x * TPB + threadIdx.x;
    float m = 0.0f;
    if (q < GQ) {
        m = partial[q];
        #pragma unroll
        for (int c = 1; c < C_CHUNKS; ++c)
            m = fminf(m, partial[(size_t)c * GQ + q]);
    }
    // wave reduce (64 lanes)
    #pragma unroll
    for (int off = 32; off > 0; off >>= 1) m += __shfl_down(m, off);
    __shared__ float red[TPB / 64];
    if ((threadIdx.x & 63) == 0) red[threadIdx.x >> 6] = m;
    __syncthreads();
    if (threadIdx.x == 0) {
        float s = 0.0f;
        #pragma unroll
        for (int w = 0; w < TPB / 64; ++w) s += red[w];
        atomicAdd(out, s);
    }
}

extern "C" void kernel_launch(void* const* d_in, const int* in_sizes, int n_in,
                              void* d_out, int out_size, void* d_ws, size_t ws_size,
                              hipStream_t stream)
{
    const float* recon = (const float*)d_in[0];   // (B, M, 3)
    const float* src   = (const float*)d_in[1];   // (B, N, 3)
    const float* T     = (const float*)d_in[2];   // (B, 4, 4)

    const int B = in_sizes[2] / 16;
    const int M = in_sizes[0] / (B * 3);
    const int N = in_sizes[1] / (B * 3);
    const int GQ = B * (N + M);

    float4* preds   = (float4*)d_ws;                          // B*M
    float4* gts     = preds + (size_t)B * M;                  // B*N
    float*  partial = (float*)(gts + (size_t)B * N);          // C_CHUNKS * GQ
    float*  out     = (float*)d_out;

    prep_kernel<<<dim3((GQ + TPB - 1) / TPB), dim3(TPB), 0, stream>>>(
        recon, src, T, preds, gts, out, out_size, B, N, M);

    const int NAmax = (N > M) ? N : M;
    const int QT    = (NAmax + QPB - 1) / QPB;
    dim3 grid(QT * C_CHUNKS, B, 2);
    chamfer_kernel<<<grid, dim3(TPB), 0, stream>>>(gts, preds, partial, B, N, M, GQ);

    reduce_kernel<<<dim3((GQ + TPB - 1) / TPB), dim3(TPB), 0, stream>>>(partial, out, GQ);
}

// Round 9
// 87.941 us; speedup vs baseline: 1.5206x; 1.0198x over previous
//
#include <hip/hip_runtime.h>
#include <math.h>

#define TPB       256
#define KA        8                  // queries per thread
#define QPB       (TPB * KA)         // 2048 queries per block
#define C_CHUNKS  32                 // B-set split across blocks
#define CPTS      128                // points per chunk (4096/32)
#define CHUNK_F   (CPTS * 4)         // 512 floats per chunk (SoA: X,Y,Z,W each 128)

typedef float v2f __attribute__((ext_vector_type(2)));

// prep: transform src->gts, pack both sets into chunked SoA:
// per (b, chunk): [X[128] | Y[128] | Z[128] | W[128]], W = |p|^2.
// Adjacent points form aligned float2 pairs for v_pk_fma_f32.
// Also zeroes d_out.
__global__ __launch_bounds__(TPB) void prep_kernel(
    const float* __restrict__ recon,   // B*M*3
    const float* __restrict__ src,     // B*N*3
    const float* __restrict__ T,       // B*16
    float* __restrict__ preds_soa,     // B*M*4
    float* __restrict__ gts_soa,       // B*N*4
    float* __restrict__ out, int out_n,
    int B, int N, int M)
{
    int idx = blockIdx.x * TPB + threadIdx.x;
    if (idx < out_n) out[idx] = 0.0f;
    int totG = B * N;
    int totP = B * M;
    if (idx < totG) {
        int b = idx / N, n = idx - b * N;
        const float* Tb = T + b * 16;
        float x = src[3*idx + 0], y = src[3*idx + 1], z = src[3*idx + 2];
        float gx = fmaf(Tb[0], x, fmaf(Tb[1], y, fmaf(Tb[2],  z, Tb[3])));
        float gy = fmaf(Tb[4], x, fmaf(Tb[5], y, fmaf(Tb[6],  z, Tb[7])));
        float gz = fmaf(Tb[8], x, fmaf(Tb[9], y, fmaf(Tb[10], z, Tb[11])));
        size_t base = ((size_t)b * (N / CPTS) + (n >> 7)) * CHUNK_F + (n & 127);
        gts_soa[base      ] = gx;
        gts_soa[base + 128] = gy;
        gts_soa[base + 256] = gz;
        gts_soa[base + 384] = fmaf(gx, gx, fmaf(gy, gy, gz * gz));
    } else if (idx - totG < totP) {
        int k = idx - totG;
        int b = k / M, m = k - b * M;
        float x = recon[3*k + 0], y = recon[3*k + 1], z = recon[3*k + 2];
        size_t base = ((size_t)b * (M / CPTS) + (m >> 7)) * CHUNK_F + (m & 127);
        preds_soa[base      ] = x;
        preds_soa[base + 128] = y;
        preds_soa[base + 256] = z;
        preds_soa[base + 384] = fmaf(x, x, fmaf(y, y, z * z));
    }
}

// Inner loop per point-pair per query: 3 v_pk_fma_f32 + 1 min3  (2 instr/dist).
// aw-hoist: min_j(aw+bw-2ab) = aw + min_j(bw-2ab).
// dir 0: A=gts (N queries), B=preds.  dir 1: A=preds (M queries), B=gts.
// blockIdx.x = qt * C_CHUNKS + c.
__global__ __launch_bounds__(TPB, 4) void chamfer_kernel(
    const float* __restrict__ gts_soa,
    const float* __restrict__ preds_soa,
    float* __restrict__ partial,       // [C_CHUNKS][GQ]
    int B, int N, int M, int GQ)
{
    __shared__ __align__(16) float sL[CHUNK_F];   // one B-chunk, SoA (2 KiB)

    const int dir = blockIdx.z;
    const int b   = blockIdx.y;
    const int c   = blockIdx.x % C_CHUNKS;
    const int qt  = blockIdx.x / C_CHUNKS;

    const int NA  = (dir == 0) ? N : M;
    const int NB_ = (dir == 0) ? M : N;
    if (qt * QPB >= NA) return;

    const float* __restrict__ Asoa = (dir == 0) ? gts_soa : preds_soa;
    const float* __restrict__ Bsoa = (dir == 0) ? preds_soa : gts_soa;
    const int gq_base = ((dir == 0) ? 0 : B * N) + b * NA;

    // Stage this chunk (2 KiB, linear) into LDS: 128 threads x 16B.
    {
        const float4* gsrc = (const float4*)(Bsoa + ((size_t)b * (NB_ / CPTS) + c) * CHUNK_F);
        if (threadIdx.x < CPTS) ((float4*)sL)[threadIdx.x] = gsrc[threadIdx.x];
    }
    __syncthreads();

    // Load KA queries from SoA (coalesced per component); pack -2*comp pairs.
    float aw[KA], mA[KA], mB[KA];
    v2f A2X[KA], A2Y[KA], A2Z[KA];
    int qi0 = qt * QPB + (int)threadIdx.x;
    #pragma unroll
    for (int k = 0; k < KA; ++k) {
        int q = qi0 + k * TPB;                       // always < NA for valid qt
        const float* ab = Asoa + ((size_t)b * (NA / CPTS) + (q >> 7)) * CHUNK_F + (q & 127);
        float ax = ab[0], ay = ab[128], az = ab[256];
        aw[k] = ab[384];
        float tx = -2.0f * ax, ty = -2.0f * ay, tz = -2.0f * az;
        A2X[k].x = tx; A2X[k].y = tx;
        A2Y[k].x = ty; A2Y[k].y = ty;
        A2Z[k].x = tz; A2Z[k].y = tz;
        mA[k] = INFINITY; mB[k] = INFINITY;
    }

    const v2f* sX = (const v2f*)(sL +   0);   // 64 pairs
    const v2f* sY = (const v2f*)(sL + 128);
    const v2f* sZ = (const v2f*)(sL + 256);
    const v2f* sW = (const v2f*)(sL + 384);

    // 64 pair-steps, unrolled x2 (two independent min chains).
    for (int jj = 0; jj < CPTS / 2; jj += 2) {
        v2f x0 = sX[jj],   y0 = sY[jj],   z0 = sZ[jj],   w0 = sW[jj];
        v2f x1 = sX[jj+1], y1 = sY[jj+1], z1 = sZ[jj+1], w1 = sW[jj+1];
        #pragma unroll
        for (int k = 0; k < KA; ++k) {
            v2f d0, d1;
            asm("v_pk_fma_f32 %0, %1, %2, %3" : "=v"(d0) : "v"(A2Z[k]), "v"(z0), "v"(w0));
            asm("v_pk_fma_f32 %0, %1, %2, %0" : "+v"(d0) : "v"(A2Y[k]), "v"(y0));
            asm("v_pk_fma_f32 %0, %1, %2, %0" : "+v"(d0) : "v"(A2X[k]), "v"(x0));
            asm("v_pk_fma_f32 %0, %1, %2, %3" : "=v"(d1) : "v"(A2Z[k]), "v"(z1), "v"(w1));
            asm("v_pk_fma_f32 %0, %1, %2, %0" : "+v"(d1) : "v"(A2Y[k]), "v"(y1));
            asm("v_pk_fma_f32 %0, %1, %2, %0" : "+v"(d1) : "v"(A2X[k]), "v"(x1));
            mA[k] = fminf(fminf(mA[k], d0.x), d0.y);   // -> v_min3_f32
            mB[k] = fminf(fminf(mB[k], d1.x), d1.y);
        }
    }

    // Coalesced partial writes (aw added back after the min).
    #pragma unroll
    for (int k = 0; k < KA; ++k) {
        int q = qi0 + k * TPB;
        partial[(size_t)c * GQ + gq_base + q] = aw[k] + fminf(mA[k], mB[k]);
    }
}

// Combine: per-query min over chunks, then global sum.
__global__ __launch_bounds__(TPB) void reduce_kernel(
    const float* __restrict__ partial, float* __restrict__ out, int GQ)
{
    int q = blockIdx.x * TPB + threadIdx.x;
    float m = 0.0f;
    if (q < GQ) {
        m = partial[q];
        #pragma unroll
        for (int c = 1; c < C_CHUNKS; ++c)
            m = fminf(m, partial[(size_t)c * GQ + q]);
    }
    #pragma unroll
    for (int off = 32; off > 0; off >>= 1) m += __shfl_down(m, off);
    __shared__ float red[TPB / 64];
    if ((threadIdx.x & 63) == 0) red[threadIdx.x >> 6] = m;
    __syncthreads();
    if (threadIdx.x == 0) {
        float s = 0.0f;
        #pragma unroll
        for (int w = 0; w < TPB / 64; ++w) s += red[w];
        atomicAdd(out, s);
    }
}

extern "C" void kernel_launch(void* const* d_in, const int* in_sizes, int n_in,
                              void* d_out, int out_size, void* d_ws, size_t ws_size,
                              hipStream_t stream)
{
    const float* recon = (const float*)d_in[0];   // (B, M, 3)
    const float* src   = (const float*)d_in[1];   // (B, N, 3)
    const float* T     = (const float*)d_in[2];   // (B, 4, 4)

    const int B = in_sizes[2] / 16;
    const int M = in_sizes[0] / (B * 3);
    const int N = in_sizes[1] / (B * 3);
    const int GQ = B * (N + M);

    float* preds_soa = (float*)d_ws;                            // B*M*4 floats
    float* gts_soa   = preds_soa + (size_t)B * M * 4;           // B*N*4 floats
    float* partial   = gts_soa + (size_t)B * N * 4;             // C_CHUNKS * GQ
    float* out       = (float*)d_out;

    prep_kernel<<<dim3((GQ + TPB - 1) / TPB), dim3(TPB), 0, stream>>>(
        recon, src, T, preds_soa, gts_soa, out, out_size, B, N, M);

    const int NAmax = (N > M) ? N : M;
    const int QT    = (NAmax + QPB - 1) / QPB;
    dim3 grid(QT * C_CHUNKS, B, 2);
    chamfer_kernel<<<grid, dim3(TPB), 0, stream>>>(gts_soa, preds_soa, partial, B, N, M, GQ);

    reduce_kernel<<<dim3((GQ + TPB - 1) / TPB), dim3(TPB), 0, stream>>>(partial, out, GQ);
}